// Round 1
// baseline (355.802 us; speedup 1.0000x reference)
//
#include <hip/hip_runtime.h>

typedef __bf16 bf16x8 __attribute__((ext_vector_type(8)));
typedef float  f32x4  __attribute__((ext_vector_type(4)));

#define N_SITES 400000
#define KVOL    27

// Repack fp32 kernel [27][64][64] -> bf16 B-fragments in ws.
// Fragment layout (consistent-kappa): position (lane, e) of frag (ko, ks, cb)
// holds kernel[ko][ci][co] with ci = ks*32 + (lane>>4)*8 + e, co = cb*16 + (lane&15).
__global__ __launch_bounds__(256) void conv_prep(const float* __restrict__ kern,
                                                 bf16x8* __restrict__ wsb) {
    int tid = blockIdx.x * 256 + threadIdx.x;
    if (tid >= KVOL * 2 * 4 * 64) return;
    int lane = tid & 63;
    int cb   = (tid >> 6) & 3;
    int ks   = (tid >> 8) & 1;
    int ko   = tid >> 9;
    int i = lane & 15, g = lane >> 4;
    int co = cb * 16 + i;
    bf16x8 v;
#pragma unroll
    for (int e = 0; e < 8; ++e) {
        int ci = ks * 32 + g * 8 + e;
        v[e] = (__bf16)kern[(ko * 64 + ci) * 64 + co];
    }
    wsb[tid] = v;
}

__global__ __launch_bounds__(256) void conv_main(
    const float* __restrict__ feats,
    const int*   __restrict__ nmap,
    const float* __restrict__ bias,
    const bf16x8* __restrict__ wsb,
    float* __restrict__ out)
{
    const int lane = threadIdx.x & 63;
    const int wave = threadIdx.x >> 6;
    const int i = lane & 15;   // A-row / B-col / C-col within 16-tile
    const int g = lane >> 4;   // k-group
    const int row0 = (blockIdx.x * 4 + wave) * 32;   // this wave's 32 rows

    f32x4 acc[2][4] = {};      // [row-tile][col-block], 32 f32 accum regs

    for (int k = 0; k < KVOL; ++k) {
        // B fragments for this offset: 2 k-steps x 4 col-blocks, 16B/lane each
        bf16x8 bfr[2][4];
#pragma unroll
        for (int ks = 0; ks < 2; ++ks)
#pragma unroll
            for (int cb = 0; cb < 4; ++cb)
                bfr[ks][cb] = wsb[(k * 8 + ks * 4 + cb) * 64 + lane];

#pragma unroll
        for (int t = 0; t < 2; ++t) {
            const int row = row0 + t * 16 + i;
            const int idx = nmap[k * N_SITES + row];
            const int src = idx < 0 ? 0 : idx;          // clamp: row 0 stays L1-hot
            const f32x4* fp = (const f32x4*)(feats + (size_t)src * 64 + g * 8);
            f32x4 v0 = fp[0];   // ci = g*8 .. +3        (kstep 0)
            f32x4 v1 = fp[1];   // ci = g*8+4 .. +7
            f32x4 v2 = fp[8];   // ci = 32 + g*8 .. +3   (kstep 1)
            f32x4 v3 = fp[9];   // ci = 32 + g*8+4 .. +7

            union { bf16x8 v; unsigned u[4]; } A0, A1;
#pragma unroll
            for (int e = 0; e < 4; ++e) {
                A0.v[e]     = (__bf16)v0[e];
                A0.v[e + 4] = (__bf16)v1[e];
                A1.v[e]     = (__bf16)v2[e];
                A1.v[e + 4] = (__bf16)v3[e];
            }
            // zero the fragment for invalid neighbors (select, no divergence)
#pragma unroll
            for (int e = 0; e < 4; ++e) {
                A0.u[e] = (idx < 0) ? 0u : A0.u[e];
                A1.u[e] = (idx < 0) ? 0u : A1.u[e];
            }

#pragma unroll
            for (int cb = 0; cb < 4; ++cb)
                acc[t][cb] = __builtin_amdgcn_mfma_f32_16x16x32_bf16(
                                 A0.v, bfr[0][cb], acc[t][cb], 0, 0, 0);
#pragma unroll
            for (int cb = 0; cb < 4; ++cb)
                acc[t][cb] = __builtin_amdgcn_mfma_f32_16x16x32_bf16(
                                 A1.v, bfr[1][cb], acc[t][cb], 0, 0, 0);
        }
    }

    // Epilogue: C/D layout col = lane&15, row = (lane>>4)*4 + reg
    float bv[4];
#pragma unroll
    for (int cb = 0; cb < 4; ++cb) bv[cb] = bias[cb * 16 + i];

#pragma unroll
    for (int t = 0; t < 2; ++t)
#pragma unroll
        for (int cb = 0; cb < 4; ++cb)
#pragma unroll
            for (int r = 0; r < 4; ++r)
                out[(size_t)(row0 + t * 16 + g * 4 + r) * 64 + cb * 16 + i] =
                    acc[t][cb][r] + bv[cb];
}

extern "C" void kernel_launch(void* const* d_in, const int* in_sizes, int n_in,
                              void* d_out, int out_size, void* d_ws, size_t ws_size,
                              hipStream_t stream) {
    const float* feats = (const float*)d_in[0];
    const float* kern  = (const float*)d_in[1];
    const float* bias  = (const float*)d_in[2];
    const int*   nmap  = (const int*)d_in[3];
    float* out = (float*)d_out;
    bf16x8* wsb = (bf16x8*)d_ws;   // needs 27*2*4*64*16 B = 221,184 B

    // Repack weights to bf16 MFMA fragments (deterministic, every call)
    conv_prep<<<(KVOL * 2 * 4 * 64 + 255) / 256, 256, 0, stream>>>(kern, wsb);

    // 4 waves/block, 32 rows/wave -> 128 rows/block; 400000/128 = 3125 exactly
    conv_main<<<3125, 256, 0, stream>>>(feats, nmap, bias, wsb, out);
}

// Round 2
// 223.299 us; speedup vs baseline: 1.5934x; 1.5934x over previous
//
#include <hip/hip_runtime.h>

typedef __bf16 bf16x8 __attribute__((ext_vector_type(8)));
typedef float  f32x4  __attribute__((ext_vector_type(4)));

#define N_SITES 400000
#define KVOL    27
#define NPAD    (N_SITES + 16)
#define ZROW    N_SITES                      // dedicated all-zero row for invalid neighbors

// ws layout: [0, FB_BYTES) = bf16 feats (NPAD rows x 64) ; then weight fragments
#define FB_BYTES ((size_t)NPAD * 128)
#define WSB_BYTES ((size_t)KVOL * 8 * 64 * 16)
#define WS_NEED  (FB_BYTES + WSB_BYTES)

// ---------- weight repack: fp32 [27][64][64] -> bf16 MFMA B-fragments ----------
// Fragment (ko, ks, cb), position (lane, e) holds kernel[ko][ci][co],
// ci = ks*32 + (lane>>4)*8 + e, co = cb*16 + (lane&15).   (consistent-kappa)
__global__ __launch_bounds__(256) void conv_prep(const float* __restrict__ kern,
                                                 bf16x8* __restrict__ wsb) {
    int tid = blockIdx.x * 256 + threadIdx.x;
    if (tid >= KVOL * 2 * 4 * 64) return;
    int lane = tid & 63;
    int cb   = (tid >> 6) & 3;
    int ks   = (tid >> 8) & 1;
    int ko   = tid >> 9;
    int i = lane & 15, g = lane >> 4;
    int co = cb * 16 + i;
    bf16x8 v;
#pragma unroll
    for (int e = 0; e < 8; ++e) {
        int ci = ks * 32 + g * 8 + e;
        v[e] = (__bf16)kern[(ko * 64 + ci) * 64 + co];
    }
    wsb[tid] = v;
}

// ---------- feats fp32 -> bf16 (plus zero pad rows) ----------
__global__ __launch_bounds__(256) void prep_feats(const float* __restrict__ f,
                                                  bf16x8* __restrict__ dst) {
    int tid = blockIdx.x * 256 + threadIdx.x;     // one 8-elem chunk per thread
    if (tid >= NPAD * 64 / 8) return;
    bf16x8 v;
    if (tid < N_SITES * 64 / 8) {
        const f32x4* s = (const f32x4*)(f + (size_t)tid * 8);
        f32x4 a = s[0], b = s[1];
#pragma unroll
        for (int e = 0; e < 4; ++e) { v[e] = (__bf16)a[e]; v[e + 4] = (__bf16)b[e]; }
    } else {
#pragma unroll
        for (int e = 0; e < 8; ++e) v[e] = (__bf16)0.0f;
    }
    dst[tid] = v;
}

// ---------- async global->LDS stage of one offset's B fragments (8 KB) ----------
__device__ __forceinline__ void stage_b(const bf16x8* __restrict__ wsb, int k,
                                        char* buf) {
    // 8192 B = 512 chunks of 16 B; 256 threads x 2 chunks.
    // global_load_lds writes LDS at (wave-uniform base) + lane*16.
    const char* g = (const char*)(wsb + (size_t)k * 8 * 64);
    int wave = threadIdx.x >> 6;
    int t    = threadIdx.x;
    __builtin_amdgcn_global_load_lds(
        (const __attribute__((address_space(1))) char*)(g + (size_t)t * 16),
        (__attribute__((address_space(3))) char*)(buf + wave * 1024), 16, 0, 0);
    __builtin_amdgcn_global_load_lds(
        (const __attribute__((address_space(1))) char*)(g + 4096 + (size_t)t * 16),
        (__attribute__((address_space(3))) char*)(buf + 4096 + wave * 1024), 16, 0, 0);
}

// ---------- main: 16 rows/wave, 4 waves/block, B in double-buffered LDS ----------
__global__ __launch_bounds__(256, 8) void conv_main2(
    const bf16x8* __restrict__ featsb,   // [NPAD][8] bf16x8 (row = 8 chunks)
    const int*   __restrict__ nmap,
    const float* __restrict__ bias,
    const bf16x8* __restrict__ wsb,
    float* __restrict__ out)
{
    __shared__ __align__(1024) char ldsb[2][8192];

    const int lane = threadIdx.x & 63;
    const int wave = threadIdx.x >> 6;
    const int i = lane & 15;             // A-row / C-col within 16-tile
    const int g = lane >> 4;             // k-group
    const int row0 = blockIdx.x * 64 + wave * 16;
    const int myrow = row0 + i;

    f32x4 acc[4] = {};

    // prologue: gather A for k=0, stage B for k=0
    int idx0 = __builtin_nontemporal_load(&nmap[myrow]);
    const bf16x8* fr0 = featsb + (size_t)(idx0 < 0 ? ZROW : idx0) * 8 + g;
    bf16x8 a0 = fr0[0];
    bf16x8 a1 = fr0[4];
    stage_b(wsb, 0, ldsb[0]);
    int cur = 0;

    for (int k = 0; k < KVOL; ++k) {
        __syncthreads();                 // full drain: stage(k) + our gathers done
        bf16x8 a0n, a1n;
        if (k + 1 < KVOL) {
            stage_b(wsb, k + 1, ldsb[cur ^ 1]);          // in flight across barrier
            int idxn = __builtin_nontemporal_load(&nmap[(k + 1) * N_SITES + myrow]);
            const bf16x8* frn = featsb + (size_t)(idxn < 0 ? ZROW : idxn) * 8 + g;
            a0n = frn[0];                                 // latency hides under MFMA
            a1n = frn[4];
        }
        const bf16x8* B = (const bf16x8*)ldsb[cur];
#pragma unroll
        for (int cb = 0; cb < 4; ++cb) {
            bf16x8 b0 = B[cb * 64 + lane];           // ks=0 frag
            bf16x8 b1 = B[(4 + cb) * 64 + lane];     // ks=1 frag
            acc[cb] = __builtin_amdgcn_mfma_f32_16x16x32_bf16(a0, b0, acc[cb], 0, 0, 0);
            acc[cb] = __builtin_amdgcn_mfma_f32_16x16x32_bf16(a1, b1, acc[cb], 0, 0, 0);
        }
        a0 = a0n; a1 = a1n;
        cur ^= 1;
    }

    // epilogue: C/D layout col = lane&15, row = (lane>>4)*4 + reg
    float bv[4];
#pragma unroll
    for (int cb = 0; cb < 4; ++cb) bv[cb] = bias[cb * 16 + i];
#pragma unroll
    for (int cb = 0; cb < 4; ++cb)
#pragma unroll
        for (int r = 0; r < 4; ++r)
            __builtin_nontemporal_store(acc[cb][r] + bv[cb],
                &out[(size_t)(row0 + g * 4 + r) * 64 + cb * 16 + i]);
}

// ---------- round-1 fallback (used only if ws_size is too small) ----------
__global__ __launch_bounds__(256) void conv_main1(
    const float* __restrict__ feats,
    const int*   __restrict__ nmap,
    const float* __restrict__ bias,
    const bf16x8* __restrict__ wsb,
    float* __restrict__ out)
{
    const int lane = threadIdx.x & 63;
    const int wave = threadIdx.x >> 6;
    const int i = lane & 15;
    const int g = lane >> 4;
    const int row0 = (blockIdx.x * 4 + wave) * 32;

    f32x4 acc[2][4] = {};

    for (int k = 0; k < KVOL; ++k) {
        bf16x8 bfr[2][4];
#pragma unroll
        for (int ks = 0; ks < 2; ++ks)
#pragma unroll
            for (int cb = 0; cb < 4; ++cb)
                bfr[ks][cb] = wsb[(k * 8 + ks * 4 + cb) * 64 + lane];
#pragma unroll
        for (int t = 0; t < 2; ++t) {
            const int row = row0 + t * 16 + i;
            const int idx = nmap[k * N_SITES + row];
            const int src = idx < 0 ? 0 : idx;
            const f32x4* fp = (const f32x4*)(feats + (size_t)src * 64 + g * 8);
            f32x4 v0 = fp[0], v1 = fp[1], v2 = fp[8], v3 = fp[9];
            union { bf16x8 v; unsigned u[4]; } A0, A1;
#pragma unroll
            for (int e = 0; e < 4; ++e) {
                A0.v[e] = (__bf16)v0[e]; A0.v[e + 4] = (__bf16)v1[e];
                A1.v[e] = (__bf16)v2[e]; A1.v[e + 4] = (__bf16)v3[e];
            }
#pragma unroll
            for (int e = 0; e < 4; ++e) {
                A0.u[e] = (idx < 0) ? 0u : A0.u[e];
                A1.u[e] = (idx < 0) ? 0u : A1.u[e];
            }
#pragma unroll
            for (int cb = 0; cb < 4; ++cb)
                acc[t][cb] = __builtin_amdgcn_mfma_f32_16x16x32_bf16(A0.v, bfr[0][cb], acc[t][cb], 0, 0, 0);
#pragma unroll
            for (int cb = 0; cb < 4; ++cb)
                acc[t][cb] = __builtin_amdgcn_mfma_f32_16x16x32_bf16(A1.v, bfr[1][cb], acc[t][cb], 0, 0, 0);
        }
    }
    float bv[4];
#pragma unroll
    for (int cb = 0; cb < 4; ++cb) bv[cb] = bias[cb * 16 + i];
#pragma unroll
    for (int t = 0; t < 2; ++t)
#pragma unroll
        for (int cb = 0; cb < 4; ++cb)
#pragma unroll
            for (int r = 0; r < 4; ++r)
                out[(size_t)(row0 + t * 16 + g * 4 + r) * 64 + cb * 16 + i] =
                    acc[t][cb][r] + bv[cb];
}

extern "C" void kernel_launch(void* const* d_in, const int* in_sizes, int n_in,
                              void* d_out, int out_size, void* d_ws, size_t ws_size,
                              hipStream_t stream) {
    const float* feats = (const float*)d_in[0];
    const float* kern  = (const float*)d_in[1];
    const float* bias  = (const float*)d_in[2];
    const int*   nmap  = (const int*)d_in[3];
    float* out = (float*)d_out;

    if (ws_size >= WS_NEED) {
        bf16x8* fb  = (bf16x8*)d_ws;
        bf16x8* wsb = (bf16x8*)((char*)d_ws + FB_BYTES);
        prep_feats<<<(NPAD * 64 / 8 + 255) / 256, 256, 0, stream>>>(feats, fb);
        conv_prep<<<(KVOL * 2 * 4 * 64 + 255) / 256, 256, 0, stream>>>(kern, wsb);
        // 16 rows/wave, 4 waves/block -> 64 rows/block; 400000/64 = 6250 exactly
        conv_main2<<<6250, 256, 0, stream>>>(fb, nmap, bias, wsb, out);
    } else {
        bf16x8* wsb = (bf16x8*)d_ws;
        conv_prep<<<(KVOL * 2 * 4 * 64 + 255) / 256, 256, 0, stream>>>(kern, wsb);
        conv_main1<<<3125, 256, 0, stream>>>(feats, nmap, bias, wsb, out);
    }
}

// Round 3
// 196.741 us; speedup vs baseline: 1.8085x; 1.1350x over previous
//
#include <hip/hip_runtime.h>

typedef __bf16 bf16x8 __attribute__((ext_vector_type(8)));
typedef float  f32x4  __attribute__((ext_vector_type(4)));

#define N_SITES 400000
#define KVOL    27
#define NPAD    (N_SITES + 16)
#define ZROW    N_SITES                  // all-zero row for invalid neighbors

#define FB_BYTES  ((size_t)NPAD * 128)
#define WSB_BYTES ((size_t)KVOL * 8 * 64 * 16)
#define WS_NEED   (FB_BYTES + WSB_BYTES)

// ---------- weight repack: fp32 [27][64][64] -> bf16 MFMA B-fragments ----------
// Fragment (ko, ks, cb), position (lane, e) holds kernel[ko][ci][co],
// ci = ks*32 + (lane>>4)*8 + e, co = cb*16 + (lane&15).
__global__ __launch_bounds__(256) void conv_prep(const float* __restrict__ kern,
                                                 bf16x8* __restrict__ wsb) {
    int tid = blockIdx.x * 256 + threadIdx.x;
    if (tid >= KVOL * 2 * 4 * 64) return;
    int lane = tid & 63;
    int cb   = (tid >> 6) & 3;
    int ks   = (tid >> 8) & 1;
    int ko   = tid >> 9;
    int i = lane & 15, g = lane >> 4;
    int co = cb * 16 + i;
    bf16x8 v;
#pragma unroll
    for (int e = 0; e < 8; ++e) {
        int ci = ks * 32 + g * 8 + e;
        v[e] = (__bf16)kern[(ko * 64 + ci) * 64 + co];
    }
    wsb[tid] = v;
}

// ---------- feats fp32 -> bf16 (plus zero pad rows) ----------
__global__ __launch_bounds__(256) void prep_feats(const float* __restrict__ f,
                                                  bf16x8* __restrict__ dst) {
    int tid = blockIdx.x * 256 + threadIdx.x;
    if (tid >= NPAD * 64 / 8) return;
    bf16x8 v;
    if (tid < N_SITES * 64 / 8) {
        const f32x4* s = (const f32x4*)(f + (size_t)tid * 8);
        f32x4 a = s[0], b = s[1];
#pragma unroll
        for (int e = 0; e < 4; ++e) { v[e] = (__bf16)a[e]; v[e + 4] = (__bf16)b[e]; }
    } else {
#pragma unroll
        for (int e = 0; e < 8; ++e) v[e] = (__bf16)0.0f;
    }
    dst[tid] = v;
}

// ---------- async global->LDS stage of one offset's B fragments (8 KB) ----------
__device__ __forceinline__ void stage_b(const bf16x8* __restrict__ wsb, int k,
                                        char* buf) {
    const char* g = (const char*)(wsb + (size_t)k * 8 * 64);
    int wave = threadIdx.x >> 6;
    int t    = threadIdx.x;
    __builtin_amdgcn_global_load_lds(
        (const __attribute__((address_space(1))) char*)(g + (size_t)t * 16),
        (__attribute__((address_space(3))) char*)(buf + wave * 1024), 16, 0, 0);
    __builtin_amdgcn_global_load_lds(
        (const __attribute__((address_space(1))) char*)(g + 4096 + (size_t)t * 16),
        (__attribute__((address_space(3))) char*)(buf + 4096 + wave * 1024), 16, 0, 0);
}

// ---------- A-fragment set: 32 rows (2 row-tiles) x K=64 (2 halves) ----------
struct AFrag { bf16x8 a0t0, a1t0, a0t1, a1t1; };

__device__ __forceinline__ void gatherA(const bf16x8* __restrict__ fb, int g,
                                        int idx0, int idx1, AFrag& s) {
    const bf16x8* f0 = fb + (((idx0 < 0 ? ZROW : idx0) << 3) + g);
    s.a0t0 = f0[0];
    s.a1t0 = f0[4];
    const bf16x8* f1 = fb + (((idx1 < 0 ? ZROW : idx1) << 3) + g);
    s.a0t1 = f1[0];
    s.a1t1 = f1[4];
}

__device__ __forceinline__ void mfma16(const char* bbuf, int lane,
                                       const AFrag& s, f32x4 acc[2][4]) {
    const bf16x8* B = (const bf16x8*)bbuf;
#pragma unroll
    for (int cb = 0; cb < 4; ++cb) {
        bf16x8 b0 = B[cb * 64 + lane];
        bf16x8 b1 = B[(4 + cb) * 64 + lane];
        acc[0][cb] = __builtin_amdgcn_mfma_f32_16x16x32_bf16(s.a0t0, b0, acc[0][cb], 0, 0, 0);
        acc[0][cb] = __builtin_amdgcn_mfma_f32_16x16x32_bf16(s.a1t0, b1, acc[0][cb], 0, 0, 0);
        acc[1][cb] = __builtin_amdgcn_mfma_f32_16x16x32_bf16(s.a0t1, b0, acc[1][cb], 0, 0, 0);
        acc[1][cb] = __builtin_amdgcn_mfma_f32_16x16x32_bf16(s.a1t1, b1, acc[1][cb], 0, 0, 0);
    }
}

// ---------- steady-state body for iteration k (k <= 23) ----------
// vmem issue order per wave:  S_{k+1} (2 ops)  then  A_{k+2} (4 ops).
// Barrier waits vmcnt(4): drains S_{k+1} (+ older A_{k+1}), leaves A_{k+2}
// in flight across the barrier -> gathers get ~2 iterations of latency slack.
__device__ __forceinline__ void body(int k,
    const bf16x8* __restrict__ fb, const bf16x8* __restrict__ wsb,
    char (*ldsb)[8192], const int* ldsi, int lane, int wave, int g,
    AFrag& cur, AFrag& nxt2, int iu0, int iu1, int& il0, int& il1,
    f32x4 acc[2][4])
{
    __builtin_amdgcn_sched_barrier(0);
    stage_b(wsb, k + 1, ldsb[(k + 1) & 1]);      // 2 vmem (must stay first)
    __builtin_amdgcn_sched_barrier(0);
    gatherA(fb, g, iu0, iu1, nxt2);              // 4 vmem, for k+2
    il0 = ldsi[(k + 3) * 128 + wave * 32 + (lane & 15)];        // idx(k+3) via LDS
    il1 = ldsi[(k + 3) * 128 + wave * 32 + 16 + (lane & 15)];
    __builtin_amdgcn_sched_barrier(0);
    mfma16(ldsb[k & 1], lane, cur, acc);
    __builtin_amdgcn_sched_barrier(0);
    asm volatile("s_waitcnt vmcnt(4)" ::: "memory");
    __builtin_amdgcn_sched_barrier(0);
    __builtin_amdgcn_s_barrier();
}

__global__ __launch_bounds__(256, 3) void conv_main3(
    const bf16x8* __restrict__ featsb,
    const int*   __restrict__ nmap,
    const float* __restrict__ bias,
    const bf16x8* __restrict__ wsb,
    float* __restrict__ out)
{
    __shared__ __align__(1024) char ldsb[2][8192];
    __shared__ __align__(16)   int  ldsi[KVOL * 128];   // block's nmap slab

    const int lane = threadIdx.x & 63;
    const int wave = threadIdx.x >> 6;
    const int i = lane & 15;
    const int g = lane >> 4;
    const int brow = blockIdx.x * 128;
    const int row0 = brow + wave * 32;

    // ---- prologue: stage nmap slab (27 x 128 ints = 864 x 16B chunks) ----
    {
        const int* nsrc = nmap + brow;
#pragma unroll
        for (int r = 0; r < 3; ++r) {
            int c = r * 256 + threadIdx.x;
            int k = c >> 5, j = c & 31;
            __builtin_amdgcn_global_load_lds(
                (const __attribute__((address_space(1))) char*)
                    ((const char*)(nsrc + (size_t)k * N_SITES + j * 4)),
                (__attribute__((address_space(3))) char*)
                    ((char*)ldsi + (r * 256 + wave * 64) * 16),
                16, 0, 0);
        }
        int c = 768 + threadIdx.x;
        if (c < KVOL * 32) {
            int k = c >> 5, j = c & 31;
            __builtin_amdgcn_global_load_lds(
                (const __attribute__((address_space(1))) char*)
                    ((const char*)(nsrc + (size_t)k * N_SITES + j * 4)),
                (__attribute__((address_space(3))) char*)
                    ((char*)ldsi + (768 + wave * 64) * 16),
                16, 0, 0);
        }
    }
    stage_b(wsb, 0, ldsb[0]);

    float bv[4];
#pragma unroll
    for (int cb = 0; cb < 4; ++cb) bv[cb] = bias[cb * 16 + i];

    __syncthreads();   // full drain once: nmap slab + B(0) ready

    f32x4 acc[2][4] = {};
    AFrag S0, S1, S2;
    int I0t0, I0t1, I1t0, I1t1, I2t0, I2t1;

    I0t0 = ldsi[0 * 128 + wave * 32 + i];  I0t1 = ldsi[0 * 128 + wave * 32 + 16 + i];
    I1t0 = ldsi[1 * 128 + wave * 32 + i];  I1t1 = ldsi[1 * 128 + wave * 32 + 16 + i];
    I2t0 = ldsi[2 * 128 + wave * 32 + i];  I2t1 = ldsi[2 * 128 + wave * 32 + 16 + i];
    gatherA(featsb, g, I0t0, I0t1, S0);    // A_0
    gatherA(featsb, g, I1t0, I1t1, S1);    // A_1

    // slots: iter k uses S[k%3]; writes S[(k+2)%3]; consumes I[(k+2)%3]; loads I[k%3]
#pragma unroll 1
    for (int j = 0; j < 8; ++j) {
        int k = j * 3;
        body(k,     featsb, wsb, ldsb, ldsi, lane, wave, g, S0, S2, I2t0, I2t1, I0t0, I0t1, acc);
        body(k + 1, featsb, wsb, ldsb, ldsi, lane, wave, g, S1, S0, I0t0, I0t1, I1t0, I1t1, acc);
        body(k + 2, featsb, wsb, ldsb, ldsi, lane, wave, g, S2, S1, I1t0, I1t1, I2t0, I2t1, acc);
    }

    // ---- epilogue: k = 24, 25, 26 ----
    // k=24: stage S_25, gather A_26 (idx from I2, loaded at k=23)
    __builtin_amdgcn_sched_barrier(0);
    stage_b(wsb, 25, ldsb[1]);
    __builtin_amdgcn_sched_barrier(0);
    gatherA(featsb, g, I2t0, I2t1, S2);
    __builtin_amdgcn_sched_barrier(0);
    mfma16(ldsb[0], lane, S0, acc);
    __builtin_amdgcn_sched_barrier(0);
    asm volatile("s_waitcnt vmcnt(4)" ::: "memory");
    __builtin_amdgcn_sched_barrier(0);
    __builtin_amdgcn_s_barrier();
    // k=25: stage S_26 (buf0), MFMA S1 from buf1
    __builtin_amdgcn_sched_barrier(0);
    stage_b(wsb, 26, ldsb[0]);
    __builtin_amdgcn_sched_barrier(0);
    mfma16(ldsb[1], lane, S1, acc);
    __builtin_amdgcn_sched_barrier(0);
    asm volatile("s_waitcnt vmcnt(0)" ::: "memory");
    __builtin_amdgcn_sched_barrier(0);
    __builtin_amdgcn_s_barrier();
    // k=26
    mfma16(ldsb[0], lane, S2, acc);

    // ---- epilogue stores: C/D layout col = lane&15, row = (lane>>4)*4 + reg ----
#pragma unroll
    for (int t = 0; t < 2; ++t)
#pragma unroll
        for (int cb = 0; cb < 4; ++cb)
#pragma unroll
            for (int r = 0; r < 4; ++r)
                __builtin_nontemporal_store(acc[t][cb][r] + bv[cb],
                    &out[(size_t)(row0 + t * 16 + g * 4 + r) * 64 + cb * 16 + i]);
}

// ---------- fallback (only if ws too small): round-1 kernel ----------
__global__ __launch_bounds__(256) void conv_main1(
    const float* __restrict__ feats,
    const int*   __restrict__ nmap,
    const float* __restrict__ bias,
    const bf16x8* __restrict__ wsb,
    float* __restrict__ out)
{
    const int lane = threadIdx.x & 63;
    const int wave = threadIdx.x >> 6;
    const int i = lane & 15;
    const int g = lane >> 4;
    const int row0 = (blockIdx.x * 4 + wave) * 32;

    f32x4 acc[2][4] = {};
    for (int k = 0; k < KVOL; ++k) {
        bf16x8 bfr[2][4];
#pragma unroll
        for (int ks = 0; ks < 2; ++ks)
#pragma unroll
            for (int cb = 0; cb < 4; ++cb)
                bfr[ks][cb] = wsb[(k * 8 + ks * 4 + cb) * 64 + lane];
#pragma unroll
        for (int t = 0; t < 2; ++t) {
            const int row = row0 + t * 16 + i;
            const int idx = nmap[k * N_SITES + row];
            const int src = idx < 0 ? 0 : idx;
            const f32x4* fp = (const f32x4*)(feats + (size_t)src * 64 + g * 8);
            f32x4 v0 = fp[0], v1 = fp[1], v2 = fp[8], v3 = fp[9];
            union { bf16x8 v; unsigned u[4]; } A0, A1;
#pragma unroll
            for (int e = 0; e < 4; ++e) {
                A0.v[e] = (__bf16)v0[e]; A0.v[e + 4] = (__bf16)v1[e];
                A1.v[e] = (__bf16)v2[e]; A1.v[e + 4] = (__bf16)v3[e];
            }
#pragma unroll
            for (int e = 0; e < 4; ++e) {
                A0.u[e] = (idx < 0) ? 0u : A0.u[e];
                A1.u[e] = (idx < 0) ? 0u : A1.u[e];
            }
#pragma unroll
            for (int cb = 0; cb < 4; ++cb)
                acc[t][cb] = __builtin_amdgcn_mfma_f32_16x16x32_bf16(A0.v, bfr[0][cb], acc[t][cb], 0, 0, 0);
#pragma unroll
            for (int cb = 0; cb < 4; ++cb)
                acc[t][cb] = __builtin_amdgcn_mfma_f32_16x16x32_bf16(A1.v, bfr[1][cb], acc[t][cb], 0, 0, 0);
        }
    }
    float bv[4];
#pragma unroll
    for (int cb = 0; cb < 4; ++cb) bv[cb] = bias[cb * 16 + i];
#pragma unroll
    for (int t = 0; t < 2; ++t)
#pragma unroll
        for (int cb = 0; cb < 4; ++cb)
#pragma unroll
            for (int r = 0; r < 4; ++r)
                out[(size_t)(row0 + t * 16 + g * 4 + r) * 64 + cb * 16 + i] =
                    acc[t][cb][r] + bv[cb];
}

extern "C" void kernel_launch(void* const* d_in, const int* in_sizes, int n_in,
                              void* d_out, int out_size, void* d_ws, size_t ws_size,
                              hipStream_t stream) {
    const float* feats = (const float*)d_in[0];
    const float* kern  = (const float*)d_in[1];
    const float* bias  = (const float*)d_in[2];
    const int*   nmap  = (const int*)d_in[3];
    float* out = (float*)d_out;

    if (ws_size >= WS_NEED) {
        bf16x8* fb  = (bf16x8*)d_ws;
        bf16x8* wsb = (bf16x8*)((char*)d_ws + FB_BYTES);
        prep_feats<<<(NPAD * 64 / 8 + 255) / 256, 256, 0, stream>>>(feats, fb);
        conv_prep<<<(KVOL * 2 * 4 * 64 + 255) / 256, 256, 0, stream>>>(kern, wsb);
        // 32 rows/wave, 4 waves/block -> 128 rows/block; 400000/128 = 3125 exactly
        conv_main3<<<3125, 256, 0, stream>>>(fb, nmap, bias, wsb, out);
    } else {
        bf16x8* wsb = (bf16x8*)d_ws;
        conv_prep<<<(KVOL * 2 * 4 * 64 + 255) / 256, 256, 0, stream>>>(kern, wsb);
        conv_main1<<<3125, 256, 0, stream>>>(feats, nmap, bias, wsb, out);
    }
}